// Round 4
// baseline (1315.168 us; speedup 1.0000x reference)
//
#include <hip/hip_runtime.h>
#include <cmath>

#define WIN 64
#define HID 512
#define BATCH 1024
#define KIN 518

typedef _Float16 f16;
typedef _Float16 half8 __attribute__((ext_vector_type(8)));
typedef float f32x4 __attribute__((ext_vector_type(4)));

struct Sched { int starts[63]; int ends[63]; };
struct SegMap { int idx[64]; };
struct GSteps { int g[32]; int n; };

// ---------------------------------------------------------------------------
// Builder: dense per-position flag tables for the scan kernel.
// ---------------------------------------------------------------------------
__global__ __launch_bounds__(1024)
void build_flags(int* __restrict__ fe, int* __restrict__ sidx, Sched sc) {
  int tid = threadIdx.x;
  if (tid < 1000) fe[tid] = -1;
  __syncthreads();
  if (tid < 63) {
    fe[sc.ends[tid]] = tid;
    sidx[tid] = sc.starts[tid] / 50;
  }
}

// ---------------------------------------------------------------------------
// Parallel logsig scan (validated round 3). Writes lsh[t][b][64] fp16.
// ---------------------------------------------------------------------------
__global__ __launch_bounds__(256)
void logsig_scan(const float* __restrict__ z, const int* __restrict__ fe,
                 const int* __restrict__ sidx, ushort* __restrict__ lsh,
                 float scale) {
  __shared__ float zs[3000];
  __shared__ float Cs[20][3];
  __shared__ float wtot[4][6];
  __shared__ float earr[63][6];
  const int tid = threadIdx.x;
  const int b = blockIdx.x;
  const int ln = tid & 63, wv = tid >> 6;

  const float4* zrow = (const float4*)(z + (size_t)b * 3000);
  for (int i = tid; i < 750; i += 256) ((float4*)zs)[i] = zrow[i];
  if (tid == 0) { Cs[0][0] = 0.f; Cs[0][1] = 0.f; Cs[0][2] = 0.f; }

  const int p0 = 4 * tid + 1;
  int myfe[4];
#pragma unroll
  for (int i = 0; i < 4; ++i) myfe[i] = (p0 + i <= 999) ? fe[p0 + i] : -1;
  __syncthreads();

  float d0 = 0.f, d1 = 0.f, d2 = 0.f, A0 = 0.f, A1 = 0.f, A2 = 0.f;
  if (p0 <= 999) {
    float b0 = 0.f, b1 = 0.f, b2 = 0.f;
#pragma unroll
    for (int i = 0; i < 4; ++i) {
      int p = p0 + i;
      if (p > 999) break;
      float n0 = b0 + zs[p * 3 + 0] * scale;
      float n1 = b1 + zs[p * 3 + 1] * scale;
      float n2 = b2 + zs[p * 3 + 2] * scale;
      A0 += 0.5f * (b0 * n1 - b1 * n0);
      A1 += 0.5f * (b0 * n2 - b2 * n0);
      A2 += 0.5f * (b1 * n2 - b2 * n1);
      b0 = n0; b1 = n1; b2 = n2;
    }
    d0 = b0; d1 = b1; d2 = b2;
  }

#pragma unroll
  for (int off = 1; off < 64; off <<= 1) {
    float e0 = __shfl(d0, ln - off), e1 = __shfl(d1, ln - off), e2 = __shfl(d2, ln - off);
    float eA0 = __shfl(A0, ln - off), eA1 = __shfl(A1, ln - off), eA2 = __shfl(A2, ln - off);
    if (ln >= off) {
      A0 = eA0 + A0 + 0.5f * (e0 * d1 - e1 * d0);
      A1 = eA1 + A1 + 0.5f * (e0 * d2 - e2 * d0);
      A2 = eA2 + A2 + 0.5f * (e1 * d2 - e2 * d1);
      d0 += e0; d1 += e1; d2 += e2;
    }
  }
  if (ln == 63) {
    wtot[wv][0] = d0; wtot[wv][1] = d1; wtot[wv][2] = d2;
    wtot[wv][3] = A0; wtot[wv][4] = A1; wtot[wv][5] = A2;
  }
  __syncthreads();

  float P0 = 0.f, P1 = 0.f, P2 = 0.f, PA0 = 0.f, PA1 = 0.f, PA2 = 0.f;
  for (int w = 0; w < wv; ++w) {
    float t0 = wtot[w][0], t1 = wtot[w][1], t2 = wtot[w][2];
    PA0 = PA0 + wtot[w][3] + 0.5f * (P0 * t1 - P1 * t0);
    PA1 = PA1 + wtot[w][4] + 0.5f * (P0 * t2 - P2 * t0);
    PA2 = PA2 + wtot[w][5] + 0.5f * (P1 * t2 - P2 * t1);
    P0 += t0; P1 += t1; P2 += t2;
  }
  float L0 = __shfl(d0, ln - 1), L1 = __shfl(d1, ln - 1), L2 = __shfl(d2, ln - 1);
  float LA0 = __shfl(A0, ln - 1), LA1 = __shfl(A1, ln - 1), LA2 = __shfl(A2, ln - 1);
  if (ln == 0) { L0 = L1 = L2 = LA0 = LA1 = LA2 = 0.f; }
  float bp0 = P0 + L0, bp1 = P1 + L1, bp2 = P2 + L2;
  float C0 = PA0 + LA0 + 0.5f * (P0 * L1 - P1 * L0);
  float C1 = PA1 + LA1 + 0.5f * (P0 * L2 - P2 * L0);
  float C2 = PA2 + LA2 + 0.5f * (P1 * L2 - P2 * L1);

  if (p0 <= 999) {
#pragma unroll
    for (int i = 0; i < 4; ++i) {
      int p = p0 + i;
      if (p > 999) break;
      float n0 = bp0 + zs[p * 3 + 0] * scale;
      float n1 = bp1 + zs[p * 3 + 1] * scale;
      float n2 = bp2 + zs[p * 3 + 2] * scale;
      C0 += 0.5f * (bp0 * n1 - bp1 * n0);
      C1 += 0.5f * (bp0 * n2 - bp2 * n0);
      C2 += 0.5f * (bp1 * n2 - bp2 * n1);
      bp0 = n0; bp1 = n1; bp2 = n2;
      if (p % 50 == 0) {
        int s = p / 50;
        Cs[s][0] = C0; Cs[s][1] = C1; Cs[s][2] = C2;
      }
      int k = myfe[i];
      if (k >= 0) {
        earr[k][0] = bp0; earr[k][1] = bp1; earr[k][2] = bp2;
        earr[k][3] = C0;  earr[k][4] = C1;  earr[k][5] = C2;
      }
    }
  }
  __syncthreads();

  if (tid < 63) {
    int s = sidx[tid];
    half8 v = {};
    v[0] = (f16)earr[tid][0]; v[1] = (f16)earr[tid][1]; v[2] = (f16)earr[tid][2];
    v[3] = (f16)(earr[tid][3] - Cs[s][0]);
    v[4] = (f16)(earr[tid][4] - Cs[s][1]);
    v[5] = (f16)(earr[tid][5] - Cs[s][2]);
    half8 zz = {};
    half8* d = (half8*)(lsh + ((size_t)(tid + 1) * BATCH + b) * 64);
    d[0] = v;
#pragma unroll
    for (int q = 1; q < 8; ++q) d[q] = zz;
  } else if (tid == 63) {
    half8 zz = {};
    half8* d = (half8*)(lsh + (size_t)b * 64);
#pragma unroll
    for (int q = 0; q < 8; ++q) d[q] = zz;
  }
}

// ---------------------------------------------------------------------------
// f32 -> f16 weight convert with K zero-padding.
// ---------------------------------------------------------------------------
__global__ __launch_bounds__(256)
void cvt_w(const float* __restrict__ src, ushort* __restrict__ dst,
           int N, int Ks, int Kd) {
  int i = blockIdx.x * 256 + threadIdx.x;
  int nblk = Kd >> 3;
  if (i >= N * nblk) return;
  int row = i / nblk, k = (i - row * nblk) * 8;
  half8 v;
#pragma unroll
  for (int j = 0; j < 8; ++j) {
    int kk = k + j;
    float f = (kk < Ks) ? src[(size_t)row * Ks + kk] : 0.f;
    v[j] = (f16)f;
  }
  *(half8*)&dst[(size_t)row * Kd + k] = v;
}

// ---------------------------------------------------------------------------
// Fused serial chain: ONE launch, 16 blocks x 64 batch rows, ZERO grid sync
// (the MLP chain is row-independent). h lives in LDS (64KB, XOR-swizzled
// 16B groups); W streams L2 -> registers (no reuse within a block).
// Waves split N: wave wv owns cols [wv*128, wv*128+128).
// ---------------------------------------------------------------------------
__global__ __launch_bounds__(256, 1)
void chain_kernel(const ushort* __restrict__ lsh,
                  const ushort* __restrict__ W1h,   // [512][576]
                  const ushort* __restrict__ W2h,   // [512][512]
                  const ushort* __restrict__ W3h,   // [512][512]
                  const float* __restrict__ b1,
                  const float* __restrict__ b2,
                  const float* __restrict__ b3,
                  ushort* __restrict__ Hg,          // [gs.n][1024][512]
                  GSteps gs) {
  __shared__ ushort Xs[64 * 512];                   // 64KB
  char* const xb = (char*)Xs;
  const int tid = threadIdx.x;
  const int wv = tid >> 6, ln = tid & 63;
  const int l15 = ln & 15, l4 = ln >> 4;
  const int rb = blockIdx.x * 64;                   // batch-row base
  const int nb = wv * 128;                          // n base

  f32x4 acc[4][8];

#define LDSX(r, g) (*(const half8*)(xb + (size_t)(r) * 1024 + ((((g) ^ ((r) & 7)) << 4))))

#define MFMA_KS(WPTR, LDW, KOFF)                                              \
  do {                                                                        \
    half8 xf[4], wf[8];                                                       \
    _Pragma("unroll")                                                         \
    for (int mi = 0; mi < 4; ++mi) xf[mi] = LDSX(mi * 16 + l15, ks * 4 + l4); \
    _Pragma("unroll")                                                         \
    for (int ni = 0; ni < 8; ++ni)                                            \
      wf[ni] = *(const half8*)((WPTR) + (size_t)(nb + ni * 16 + l15) * (LDW)  \
                               + (KOFF) + ks * 32 + l4 * 8);                  \
    _Pragma("unroll")                                                         \
    for (int mi = 0; mi < 4; ++mi)                                            \
      _Pragma("unroll")                                                       \
      for (int ni = 0; ni < 8; ++ni)                                          \
        acc[mi][ni] = __builtin_amdgcn_mfma_f32_16x16x32_f16(                 \
            wf[ni], xf[mi], acc[mi][ni], 0, 0, 0);                            \
  } while (0)

  // epilogue: bias+act, write swizzled LDS (and optionally global Hg slot)
#define EPI(ACT, BIAS, GPTR)                                                  \
  do {                                                                        \
    _Pragma("unroll")                                                         \
    for (int mi = 0; mi < 4; ++mi) {                                          \
      int r = mi * 16 + l15;                                                  \
      _Pragma("unroll")                                                       \
      for (int ni = 0; ni < 8; ++ni) {                                        \
        int c = nb + ni * 16 + l4 * 4;                                        \
        float4 bv = *(const float4*)&(BIAS)[c];                               \
        union { f16 h[4]; ushort4 u; } cv;                                    \
        float bb[4] = {bv.x, bv.y, bv.z, bv.w};                               \
        _Pragma("unroll")                                                     \
        for (int j4 = 0; j4 < 4; ++j4) {                                      \
          float v = acc[mi][ni][j4] + bb[j4];                                 \
          if (ACT == 1) v = fmaxf(v, 0.f);                                    \
          else { float xc = fminf(fmaxf(v, -9.f), 9.f);                       \
                 float e = __expf(2.f * xc); v = (e - 1.f) / (e + 1.f); }     \
          cv.h[j4] = (f16)v;                                                  \
        }                                                                     \
        int G = c >> 3;                                                       \
        *(ushort4*)(xb + (size_t)r * 1024 + (((G ^ (r & 7)) << 4) | ((c * 2) & 15))) = cv.u; \
        if (GPTR) *(ushort4*)((GPTR) + ((size_t)(rb + r)) * HID + c) = cv.u;  \
      }                                                                       \
    }                                                                         \
  } while (0)

  for (int j = 0; j < gs.n; ++j) {
    const int g = gs.g[j];
    // ---------------- layer 1: [h | ls_g] @ W1^T, relu ----------------
#pragma unroll
    for (int mi = 0; mi < 4; ++mi)
#pragma unroll
      for (int ni = 0; ni < 8; ++ni) acc[mi][ni] = (f32x4){0.f, 0.f, 0.f, 0.f};
    if (j > 0) {
#pragma unroll 4
      for (int ks = 0; ks < 16; ++ks) MFMA_KS(W1h, 576, 0);
    }
    // ls tail: k in [512, 576), X from lsh (global), W1h cols 512..575
#pragma unroll
    for (int kt = 0; kt < 2; ++kt) {
      half8 xf[4], wf[8];
#pragma unroll
      for (int mi = 0; mi < 4; ++mi)
        xf[mi] = *(const half8*)(lsh + ((size_t)g * BATCH + rb + mi * 16 + l15) * 64
                                 + kt * 32 + l4 * 8);
#pragma unroll
      for (int ni = 0; ni < 8; ++ni)
        wf[ni] = *(const half8*)(W1h + (size_t)(nb + ni * 16 + l15) * 576
                                 + 512 + kt * 32 + l4 * 8);
#pragma unroll
      for (int mi = 0; mi < 4; ++mi)
#pragma unroll
        for (int ni = 0; ni < 8; ++ni)
          acc[mi][ni] = __builtin_amdgcn_mfma_f32_16x16x32_f16(
              wf[ni], xf[mi], acc[mi][ni], 0, 0, 0);
    }
    __syncthreads();               // (no-op for j==0 reads; uniform anyway)
    EPI(1, b1, (ushort*)nullptr);
    __syncthreads();
    // ---------------- layer 2: relu ----------------
#pragma unroll
    for (int mi = 0; mi < 4; ++mi)
#pragma unroll
      for (int ni = 0; ni < 8; ++ni) acc[mi][ni] = (f32x4){0.f, 0.f, 0.f, 0.f};
#pragma unroll 4
    for (int ks = 0; ks < 16; ++ks) MFMA_KS(W2h, 512, 0);
    __syncthreads();
    EPI(1, b2, (ushort*)nullptr);
    __syncthreads();
    // ---------------- layer 3: tanh, write Hg[j] ----------------
#pragma unroll
    for (int mi = 0; mi < 4; ++mi)
#pragma unroll
      for (int ni = 0; ni < 8; ++ni) acc[mi][ni] = (f32x4){0.f, 0.f, 0.f, 0.f};
#pragma unroll 4
    for (int ks = 0; ks < 16; ++ks) MFMA_KS(W3h, 512, 0);
    __syncthreads();
    {
      ushort* gp = Hg + (size_t)j * (BATCH * HID);
      EPI(2, b3, gp);
    }
    __syncthreads();
  }
#undef LDSX
#undef MFMA_KS
#undef EPI
}

// ---------------------------------------------------------------------------
// fp16 MFMA GEMM (parallel phase, validated round 2/3): 128x128 tile, BK=64.
// ---------------------------------------------------------------------------
template<int ACT, int L1>
__global__ __launch_bounds__(256)
void gemm_h(const ushort* __restrict__ A, int lda, int nk,
            const ushort* __restrict__ Hg, const ushort* __restrict__ zeroh,
            const ushort* __restrict__ lsh, int chunk0, SegMap seg,
            const ushort* __restrict__ W, int ldw,
            const float* __restrict__ bias,
            ushort* __restrict__ C, int ldc) {
  __shared__ ushort lds[16384];
  char* ldsb = (char*)lds;
  const int tid = threadIdx.x;
  const int wv = tid >> 6, ln = tid & 63;
  const int bn0 = blockIdx.x * 128;
  const int br = blockIdx.y;
  const size_t gr0 = (size_t)br * 128;

  const ushort* abase = A;
  const ushort* lbase = nullptr;
  if (L1) {
    int t = chunk0 + (br >> 3);
    int sj = seg.idx[t];
    abase = (sj < 0) ? zeroh : Hg + (size_t)sj * (BATCH * HID);
    lbase = lsh + (size_t)t * BATCH * 64;
  }

  f32x4 acc[4][4];
#pragma unroll
  for (int mi = 0; mi < 4; ++mi)
#pragma unroll
    for (int ni = 0; ni < 4; ++ni) acc[mi][ni] = (f32x4){0.f, 0.f, 0.f, 0.f};

  const int xr0 = (wv >> 1) * 64, nr0 = (wv & 1) * 64;
  const int l15 = ln & 15, l4 = ln >> 4;

  for (int kt = 0; kt < nk; ++kt) {
#pragma unroll
    for (int i = 0; i < 4; ++i) {
      int q = (i * 4 + wv) * 64 + ln;
      int r = q >> 3, sl = q & 7, ss = sl ^ (r & 7);
      const ushort* src;
      if (L1) {
        int b_ = ((br & 7) << 7) + r;
        if (kt < 8) src = abase + (size_t)b_ * HID + kt * 64 + ss * 8;
        else        src = lbase + (size_t)b_ * 64 + ss * 8;
      } else {
        src = A + (gr0 + r) * (size_t)lda + kt * 64 + ss * 8;
      }
      __builtin_amdgcn_global_load_lds(
          (const __attribute__((address_space(1))) unsigned int*)src,
          (__attribute__((address_space(3))) unsigned int*)(ldsb + (i * 4 + wv) * 1024),
          16, 0, 0);
    }
#pragma unroll
    for (int i = 0; i < 4; ++i) {
      int q = (i * 4 + wv) * 64 + ln;
      int r = q >> 3, sl = q & 7, ss = sl ^ (r & 7);
      const ushort* src = W + (size_t)(bn0 + r) * ldw + kt * 64 + ss * 8;
      __builtin_amdgcn_global_load_lds(
          (const __attribute__((address_space(1))) unsigned int*)src,
          (__attribute__((address_space(3))) unsigned int*)(ldsb + 16384 + (i * 4 + wv) * 1024),
          16, 0, 0);
    }
    __syncthreads();
#pragma unroll
    for (int kk = 0; kk < 2; ++kk) {
      half8 xf[4], wf[4];
#pragma unroll
      for (int mi = 0; mi < 4; ++mi) {
        int r = xr0 + mi * 16 + l15;
        int ss = (kk * 4 + l4) ^ (r & 7);
        xf[mi] = *(const half8*)(ldsb + r * 128 + ss * 16);
      }
#pragma unroll
      for (int ni = 0; ni < 4; ++ni) {
        int r = nr0 + ni * 16 + l15;
        int ss = (kk * 4 + l4) ^ (r & 7);
        wf[ni] = *(const half8*)(ldsb + 16384 + r * 128 + ss * 16);
      }
#pragma unroll
      for (int mi = 0; mi < 4; ++mi)
#pragma unroll
        for (int ni = 0; ni < 4; ++ni)
          acc[mi][ni] = __builtin_amdgcn_mfma_f32_16x16x32_f16(wf[ni], xf[mi], acc[mi][ni], 0, 0, 0);
    }
    __syncthreads();
  }
#pragma unroll
  for (int mi = 0; mi < 4; ++mi) {
    size_t gm = gr0 + xr0 + mi * 16 + l15;
#pragma unroll
    for (int ni = 0; ni < 4; ++ni) {
      int gn = bn0 + nr0 + ni * 16 + l4 * 4;
      f32x4 a = acc[mi][ni];
      union { f16 h[4]; ushort4 u; } cv;
#pragma unroll
      for (int j = 0; j < 4; ++j) {
        float v = a[j] + bias[gn + j];
        if (ACT == 1) v = fmaxf(v, 0.f);
        else { float xc = fminf(fmaxf(v, -9.f), 9.f); float e = __expf(2.f * xc); v = (e - 1.f) / (e + 1.f); }
        cv.h[j] = (f16)v;
      }
      *(ushort4*)&C[gm * ldc + gn] = cv.u;
    }
  }
}

// ---------------------------------------------------------------------------
// out[b, tl, :] = h[row,:] @ Wout^T   (h fp16). 4 lanes/row.
// ---------------------------------------------------------------------------
__global__ __launch_bounds__(256)
void out_k(const ushort* __restrict__ H, const float* __restrict__ Wout,
           float* __restrict__ out, int chunk0) {
  const int tid = threadIdx.x;
  const int lane4 = tid & 3;
  const int row = blockIdx.x * 64 + (tid >> 2);
  const int tl = row >> 10, b = row & 1023;
  const ushort* hb = H + (size_t)row * HID;
  float a0 = 0.f, a1 = 0.f, a2 = 0.f;
#pragma unroll 4
  for (int q = 0; q < 16; ++q) {
    int k = (q * 4 + lane4) * 8;
    half8 hv = *(const half8*)&hb[k];
#pragma unroll
    for (int j = 0; j < 8; ++j) {
      float h = (float)hv[j];
      a0 += h * Wout[k + j];
      a1 += h * Wout[512 + k + j];
      a2 += h * Wout[1024 + k + j];
    }
  }
  a0 += __shfl_xor(a0, 1); a0 += __shfl_xor(a0, 2);
  a1 += __shfl_xor(a1, 1); a1 += __shfl_xor(a1, 2);
  a2 += __shfl_xor(a2, 1); a2 += __shfl_xor(a2, 2);
  if (lane4 == 0) {
    float* o = out + ((size_t)b * WIN + chunk0 + tl) * 3;
    o[0] = a0; o[1] = a1; o[2] = a2;
  }
}

// ---------------------------------------------------------------------------
extern "C" void kernel_launch(void* const* d_in, const int* in_sizes, int n_in,
                              void* d_out, int out_size, void* d_ws, size_t ws_size,
                              hipStream_t stream) {
  (void)n_in; (void)out_size; (void)ws_size; (void)in_sizes;
  const float* z    = (const float*)d_in[0];
  const float* W1   = (const float*)d_in[1];
  const float* b1   = (const float*)d_in[2];
  const float* W2   = (const float*)d_in[3];
  const float* b2   = (const float*)d_in[4];
  const float* W3   = (const float*)d_in[5];
  const float* b3   = (const float*)d_in[6];
  const float* Wout = (const float*)d_in[7];
  float* out = (float*)d_out;

  // ---- replicate _static_schedule exactly (numpy linspace doubles) ----
  double tb[1000], tt[64], tu[20];
  {
    double sb = 1.0 / 999.0; for (int i = 0; i < 1000; ++i) tb[i] = i * sb; tb[999] = 1.0;
    double st = 1.0 / 63.0;  for (int k = 0; k < 64; ++k)  tt[k] = k * st;  tt[63] = 1.0;
    for (int j = 0; j < 20; ++j) tu[j] = tb[50 * j];
  }
  auto ssr = [](const double* a, int n, double v) -> int {
    int lo = 0, hi = n;
    while (lo < hi) { int mid = (lo + hi) >> 1; if (a[mid] <= v) lo = mid + 1; else hi = mid; }
    return lo - 1;
  };
  Sched sc; int gates[64];
  {
    int u_indices[20];
    for (int j = 0; j < 20; ++j) u_indices[j] = ssr(tb, 1000, tu[j]);
    double u_times[80]; int nut = 0; int last = -1;
    for (int k = 1; k < 64; ++k) {
      int it = ssr(tb, 1000, tt[k]);
      int iu = ssr(tu, 20, tt[k]); if (iu < 0) iu = 0;
      if (iu != last) { u_times[nut++] = tu[iu]; last = iu; }
      sc.starts[k - 1] = u_indices[iu];
      sc.ends[k - 1] = it;
    }
    u_times[nut++] = tt[63];
    int qh = 0;
    for (int k = 0; k < 64; ++k) {
      if (qh < nut && tt[k] >= u_times[qh]) { ++qh; gates[k] = 1; } else gates[k] = 0;
    }
  }
  SegMap seg; GSteps gst; int ng = 0, jlast = -1;
  for (int t = 0; t < WIN; ++t) {
    seg.idx[t] = jlast;
    if (gates[t]) { if (ng < 32) gst.g[ng] = t; jlast = ng; ++ng; }
  }
  gst.n = ng - 1;   // last gated h is never consumed

  // ---- workspace carve ----
  char* p = (char*)d_ws;
  int* fe      = (int*)p;    p += 1024 * 4;
  int* sidx    = (int*)p;    p += 64 * 4;
  ushort* Hg16 = (ushort*)p; p += (size_t)22 * BATCH * HID * 2;        // 23 MB
  ushort* zeroh= (ushort*)p; p += (size_t)BATCH * HID * 2;             // 1 MB
  ushort* lsh  = (ushort*)p; p += (size_t)WIN * BATCH * 64 * 2;        // 8.4 MB
  ushort* W1h  = (ushort*)p; p += (size_t)HID * 576 * 2;
  ushort* W2h  = (ushort*)p; p += (size_t)HID * HID * 2;
  ushort* W3h  = (ushort*)p; p += (size_t)HID * HID * 2;
  ushort* A2h  = (ushort*)p; p += (size_t)WIN * BATCH * HID * 2;       // 67 MB
  ushort* A3h  = (ushort*)p; p += (size_t)WIN * BATCH * HID * 2;       // 67 MB

  hipMemsetAsync(zeroh, 0, (size_t)BATCH * HID * 2, stream);

  float scale = (float)std::sqrt(1.0 / 999.0);
  build_flags<<<1, 1024, 0, stream>>>(fe, sidx, sc);
  logsig_scan<<<BATCH, 256, 0, stream>>>(z, fe, sidx, lsh, scale);
  cvt_w<<<(HID * 72 + 255) / 256, 256, 0, stream>>>(W1, W1h, HID, KIN, 576);
  cvt_w<<<(HID * 64 + 255) / 256, 256, 0, stream>>>(W2, W2h, HID, HID, HID);
  cvt_w<<<(HID * 64 + 255) / 256, 256, 0, stream>>>(W3, W3h, HID, HID, HID);

  // ---- fused serial chain: ONE launch, no grid sync (row-independent) ----
  chain_kernel<<<BATCH / 64, 256, 0, stream>>>(lsh, W1h, W2h, W3h, b1, b2, b3,
                                               Hg16, gst);

  // ---- parallel recompute of all 64 timesteps, full width ----
  dim3 gg(4, WIN * 8), gb(256);
  gemm_h<1, 1><<<gg, gb, 0, stream>>>(A2h, HID, 9, Hg16, zeroh, lsh, 0, seg,
                                      W1h, 576, b1, A2h, HID);
  gemm_h<1, 0><<<gg, gb, 0, stream>>>(A2h, HID, 8, Hg16, zeroh, lsh, 0, seg,
                                      W2h, HID, b2, A3h, HID);
  gemm_h<2, 0><<<gg, gb, 0, stream>>>(A3h, HID, 8, Hg16, zeroh, lsh, 0, seg,
                                      W3h, HID, b3, A2h, HID);
  out_k<<<WIN * BATCH / 64, 256, 0, stream>>>(A2h, Wout, out, 0);
}